// Round 2
// baseline (331.791 us; speedup 1.0000x reference)
//
#include <hip/hip_runtime.h>
#include <hip/hip_bf16.h>
#include <stdint.h>

typedef __bf16 bf16;
typedef __bf16 bf16x4 __attribute__((ext_vector_type(4)));
typedef __bf16 bf16x8 __attribute__((ext_vector_type(8)));
typedef float f32x4 __attribute__((ext_vector_type(4)));

#define BB   2048
#define ISZ  512
#define NN   2048
#define OSZ  128

// ---------------------------------------------------------------------------
// pack: fp32 [M][W] -> bf16 dst[m][col_off + w] (row stride ld), 4 elems/thread
// ---------------------------------------------------------------------------
__global__ void pack_bf16_k(const float* __restrict__ src, bf16* __restrict__ dst,
                            int W, int ld, int col_off, int total4) {
  int idx = blockIdx.x * blockDim.x + threadIdx.x;
  if (idx >= total4) return;
  int e = idx * 4;
  int m = e / W;
  int c = e - m * W;
  const float4 v = *reinterpret_cast<const float4*>(src + e);
  bf16x4 o;
  o[0] = (bf16)v.x; o[1] = (bf16)v.y; o[2] = (bf16)v.z; o[3] = (bf16)v.w;
  *reinterpret_cast<bf16x4*>(dst + (size_t)m * ld + col_off + c) = o;
}

// ---------------------------------------------------------------------------
// transpose fp32 [K][Ncols] -> bf16 dst[n][k_off + k] (row stride ld_dst)
// MODE 0: plain   MODE 1: zero diagonal (k==n)   MODE 2: multiply by mask
// ---------------------------------------------------------------------------
template<int MODE>
__global__ void transpose_bf16_k(const float* __restrict__ src, const float* __restrict__ msk,
                                 int Ncols, bf16* __restrict__ dst, int ld_dst, int k_off) {
  __shared__ float t[32][33];
  const int k0 = blockIdx.x * 32, n0 = blockIdx.y * 32;
  const int tx = threadIdx.x, ty = threadIdx.y;
#pragma unroll
  for (int i = 0; i < 4; ++i) {
    int k = k0 + ty + i * 8;
    float v = src[(size_t)k * Ncols + n0 + tx];
    if (MODE == 1 && k == (n0 + tx)) v = 0.f;
    if (MODE == 2) v *= msk[(size_t)k * Ncols + n0 + tx];
    t[ty + i * 8][tx] = v;
  }
  __syncthreads();
#pragma unroll
  for (int i = 0; i < 4; ++i) {
    int n = n0 + ty + i * 8;
    dst[(size_t)n * ld_dst + k_off + k0 + tx] = (bf16)t[tx][ty + i * 8];
  }
}

// ---------------------------------------------------------------------------
// GEMM problem descriptor + m97-structure body (BK=32, 4 waves 2x2,
// global_load_lds width 16, 16x16x32 bf16 MFMA).
// epi 0: pre = acc + bias[col] (+ radd);  h = hin*0.9 + relu(pre)*0.1
//        -> fp32 outf + bf16 nxt
// epi 1: fp32 store of acc
// ---------------------------------------------------------------------------
struct GP {
  const bf16* A; const bf16* B;
  int K, lda, ldb;
  const float* hin; const float* bias; const float* radd;
  float* outf; int ld_out;
  bf16* nxt; int ld_nxt;
  int epi;
};

__device__ __forceinline__ void gload16(const bf16* g, bf16* l) {
  __builtin_amdgcn_global_load_lds(
      (const __attribute__((address_space(1))) void*)g,
      (__attribute__((address_space(3))) void*)l, 16, 0, 0);
}

template<int BM, int BN>
__device__ __forceinline__ void gemm_body(const GP p) {
  constexpr int BK = 32;
  constexpr int WM = BM / 2, WN = BN / 2;
  constexpr int FM = WM / 16, FN = WN / 16;
  __shared__ bf16 As[BM][BK];
  __shared__ bf16 Bs[BN][BK];
  const int tid  = threadIdx.x;
  const int lane = tid & 63;
  const int wave = tid >> 6;
  const int m0 = blockIdx.y * BM, n0 = blockIdx.x * BN;
  const int wm0 = (wave >> 1) * WM, wn0 = (wave & 1) * WN;
  const int lrow = lane >> 2;
  const int lcol = (lane & 3) * 8;
  const int frow = lane & 15;
  const int fk   = (lane >> 4) * 8;

  f32x4 acc[FM][FN];
#pragma unroll
  for (int i = 0; i < FM; ++i)
#pragma unroll
    for (int j = 0; j < FN; ++j)
#pragma unroll
      for (int r = 0; r < 4; ++r) acc[i][j][r] = 0.f;

  for (int k0 = 0; k0 < p.K; k0 += BK) {
#pragma unroll
    for (int c = wave; c < BM / 16; c += 4) {
      const bf16* g = p.A + (size_t)(m0 + c * 16 + lrow) * p.lda + k0 + lcol;
      gload16(g, &As[0][0] + c * 512);
    }
#pragma unroll
    for (int c = wave; c < BN / 16; c += 4) {
      const bf16* g = p.B + (size_t)(n0 + c * 16 + lrow) * p.ldb + k0 + lcol;
      gload16(g, &Bs[0][0] + c * 512);
    }
    __syncthreads();

    bf16x8 af[FM], bfr[FN];
#pragma unroll
    for (int i = 0; i < FM; ++i)
      af[i] = *reinterpret_cast<const bf16x8*>(&As[wm0 + i * 16 + frow][fk]);
#pragma unroll
    for (int j = 0; j < FN; ++j)
      bfr[j] = *reinterpret_cast<const bf16x8*>(&Bs[wn0 + j * 16 + frow][fk]);
#pragma unroll
    for (int i = 0; i < FM; ++i)
#pragma unroll
      for (int j = 0; j < FN; ++j)
        acc[i][j] = __builtin_amdgcn_mfma_f32_16x16x32_bf16(af[i], bfr[j], acc[i][j], 0, 0, 0);
    __syncthreads();
  }

  // epilogue: C/D layout col = lane&15, row = (lane>>4)*4 + reg
#pragma unroll
  for (int i = 0; i < FM; ++i) {
#pragma unroll
    for (int j = 0; j < FN; ++j) {
#pragma unroll
      for (int r = 0; r < 4; ++r) {
        int row = m0 + wm0 + i * 16 + (lane >> 4) * 4 + r;
        int col = n0 + wn0 + j * 16 + (lane & 15);
        float v = acc[i][j][r];
        size_t oidx = (size_t)row * p.ld_out + col;
        if (p.epi == 0) {
          float pre = v + p.bias[col];
          if (p.radd) pre += p.radd[oidx];
          float h = p.hin[oidx] * 0.9f + fmaxf(pre, 0.f) * 0.1f;
          p.outf[oidx] = h;
          p.nxt[(size_t)row * p.ld_nxt + col] = (bf16)h;
        } else {
          p.outf[oidx] = v;
        }
      }
    }
  }
}

template<int BM, int BN>
__global__ __launch_bounds__(256) void gemm_one(GP p) { gemm_body<BM, BN>(p); }

__global__ __launch_bounds__(256) void gemm_tri(GP p0, GP p1, GP p2) {
  GP p;
  if (blockIdx.z == 0) p = p0;
  else if (blockIdx.z == 1) p = p1;
  else p = p2;
  gemm_body<128, 128>(p);
}

// ---------------------------------------------------------------------------
extern "C" void kernel_launch(void* const* d_in, const int* in_sizes, int n_in,
                              void* d_out, int out_size, void* d_ws, size_t ws_size,
                              hipStream_t stream) {
  const float* x        = (const float*)d_in[0];
  const float* h0_in    = (const float*)d_in[1];
  const float* h1_in    = (const float*)d_in[2];
  const float* h2_in    = (const float*)d_in[3];
  const float* i_to_h0  = (const float*)d_in[4];
  const float* h0_w     = (const float*)d_in[5];
  const float* h0_b     = (const float*)d_in[6];
  const float* h0_to_h1 = (const float*)d_in[7];
  const float* h1_w     = (const float*)d_in[8];
  const float* h1_b     = (const float*)d_in[9];
  const float* h1_to_h2 = (const float*)d_in[10];
  const float* h2_w     = (const float*)d_in[11];
  const float* h2_b     = (const float*)d_in[12];
  const float* w_out    = (const float*)d_in[13];
  const float* m01      = (const float*)d_in[14];
  const float* m12      = (const float*)d_in[15];
  float* out = (float*)d_out;

  // workspace layout (bf16 buffers). Ah1 aliases Ar1 (dead after D1);
  // Ah2 aliases Ar2. R1/R2 live in the o_h1/o_h2 regions of d_out.
  uint8_t* ws = (uint8_t*)d_ws;
  constexpr size_t OFF_A0  = 0;                    // [2048][2560] A of S0
  constexpr size_t OFF_W0  = OFF_A0 + 10485760;    // [2048][2560] B^T of S0
  constexpr size_t OFF_W1R = OFF_W0 + 10485760;    // [2048][2048] h1_w'^T
  constexpr size_t OFF_W2R = OFF_W1R + 8388608;    // [2048][2048] h2_w'^T
  constexpr size_t OFF_W01 = OFF_W2R + 8388608;    // [2048][2048] h01m^T
  constexpr size_t OFF_W12 = OFF_W01 + 8388608;    // [2048][2048] h12m^T
  constexpr size_t OFF_WO  = OFF_W12 + 8388608;    // [128][2048]  w_out^T
  constexpr size_t OFF_AR1 = OFF_WO + 524288;      // h1_in bf16 / later h1 bf16
  constexpr size_t OFF_AR2 = OFF_AR1 + 8388608;    // h2_in bf16 / later h2 bf16
  constexpr size_t OFF_AH0 = OFF_AR2 + 8388608;    // h0 bf16
  constexpr size_t WS_NEED = OFF_AH0 + 8388608;    // ~80.2 MB
  if (ws_size < WS_NEED) return;

  bf16* A0  = (bf16*)(ws + OFF_A0);
  bf16* Wt0 = (bf16*)(ws + OFF_W0);
  bf16* W1r = (bf16*)(ws + OFF_W1R);
  bf16* W2r = (bf16*)(ws + OFF_W2R);
  bf16* W01 = (bf16*)(ws + OFF_W01);
  bf16* W12 = (bf16*)(ws + OFF_W12);
  bf16* WtO = (bf16*)(ws + OFF_WO);
  bf16* Ar1 = (bf16*)(ws + OFF_AR1);   // h1_in bf16 (R1's A); reused as Ah1
  bf16* Ar2 = (bf16*)(ws + OFF_AR2);   // h2_in bf16 (R2's A); reused as Ah2
  bf16* Ah0 = (bf16*)(ws + OFF_AH0);
  bf16* Ah1 = Ar1;
  bf16* Ah2 = Ar2;

  float* o_h0  = out;
  float* o_h1  = out + (size_t)BB * NN;
  float* o_h2  = out + (size_t)2 * BB * NN;
  float* o_out = out + (size_t)3 * BB * NN;

  // --- activation packing ---
  {
    int t4 = BB * ISZ / 4;
    pack_bf16_k<<<(t4 + 255) / 256, 256, 0, stream>>>(x, A0, ISZ, ISZ + NN, 0, t4);
  }
  {
    int t4 = BB * NN / 4;
    pack_bf16_k<<<(t4 + 255) / 256, 256, 0, stream>>>(h0_in, A0, NN, ISZ + NN, ISZ, t4);
    pack_bf16_k<<<(t4 + 255) / 256, 256, 0, stream>>>(h1_in, Ar1, NN, NN, 0, t4);
    pack_bf16_k<<<(t4 + 255) / 256, 256, 0, stream>>>(h2_in, Ar2, NN, NN, 0, t4);
  }

  // --- weight transposes (-> N x K bf16, masks/diag fused) ---
  dim3 tb(32, 8);
  transpose_bf16_k<0><<<dim3(ISZ / 32, NN / 32), tb, 0, stream>>>(i_to_h0, nullptr, NN, Wt0, ISZ + NN, 0);
  transpose_bf16_k<1><<<dim3(NN / 32, NN / 32), tb, 0, stream>>>(h0_w, nullptr, NN, Wt0, ISZ + NN, ISZ);
  transpose_bf16_k<1><<<dim3(NN / 32, NN / 32), tb, 0, stream>>>(h1_w, nullptr, NN, W1r, NN, 0);
  transpose_bf16_k<1><<<dim3(NN / 32, NN / 32), tb, 0, stream>>>(h2_w, nullptr, NN, W2r, NN, 0);
  transpose_bf16_k<2><<<dim3(NN / 32, NN / 32), tb, 0, stream>>>(h0_to_h1, m01, NN, W01, NN, 0);
  transpose_bf16_k<2><<<dim3(NN / 32, NN / 32), tb, 0, stream>>>(h1_to_h2, m12, NN, W12, NN, 0);
  transpose_bf16_k<0><<<dim3(NN / 32, OSZ / 32), tb, 0, stream>>>(w_out, nullptr, OSZ, WtO, NN, 0);

  // --- D1: S0 (h0) + R1 + R2 in one 768-block dispatch ---
  GP pS0{A0,  Wt0, ISZ + NN, ISZ + NN, ISZ + NN, h0_in, h0_b, nullptr,
         o_h0, NN, Ah0, NN, 0};
  GP pR1{Ar1, W1r, NN, NN, NN, nullptr, nullptr, nullptr, o_h1, NN, nullptr, 0, 1};
  GP pR2{Ar2, W2r, NN, NN, NN, nullptr, nullptr, nullptr, o_h2, NN, nullptr, 0, 1};
  gemm_tri<<<dim3(NN / 128, BB / 128, 3), 256, 0, stream>>>(pS0, pR1, pR2);

  // --- D2: F1 = h0@W01 (+R1) -> h1 (512 blocks) ---
  GP pF1{Ah0, W01, NN, NN, NN, h1_in, h1_b, o_h1, o_h1, NN, Ah1, NN, 0};
  gemm_one<128, 64><<<dim3(NN / 64, BB / 128), 256, 0, stream>>>(pF1);

  // --- D3: F2 = h1@W12 (+R2) -> h2 (512 blocks) ---
  GP pF2{Ah1, W12, NN, NN, NN, h2_in, h2_b, o_h2, o_h2, NN, Ah2, NN, 0};
  gemm_one<128, 64><<<dim3(NN / 64, BB / 128), 256, 0, stream>>>(pF2);

  // --- D4: out = h2 @ w_out ---
  GP pO{Ah2, WtO, NN, NN, NN, nullptr, nullptr, nullptr, o_out, OSZ, nullptr, 0, 1};
  gemm_one<32, 64><<<dim3(OSZ / 64, BB / 32), 256, 0, stream>>>(pO);
}

// Round 3
// 292.207 us; speedup vs baseline: 1.1355x; 1.1355x over previous
//
#include <hip/hip_runtime.h>
#include <hip/hip_bf16.h>
#include <stdint.h>

typedef __bf16 bf16;
typedef __bf16 bf16x4 __attribute__((ext_vector_type(4)));
typedef __bf16 bf16x8 __attribute__((ext_vector_type(8)));
typedef float f32x4 __attribute__((ext_vector_type(4)));

#define BB   2048
#define ISZ  512
#define NN   2048
#define OSZ  128

// ---------------------------------------------------------------------------
// Fused prep: 4 pack regions (fp32 -> bf16, 4 elems/thread) + 7 transposes
// (fp32 [K][N] -> bf16 dst[n][k_off+k], optional diag-zero / mask).
// All blocks are 256 threads; pack blocks first, then transpose tiles.
// ---------------------------------------------------------------------------
struct PackD { const float* src; bf16* dst; int W, ld, off, n4; };   // n4 = cumulative end (in 4-elem units)
struct TD    { const float* src; const float* msk; bf16* dst;
               int Ncols, ld_dst, k_off, mode, ntx, start; };
struct PAll  { PackD p[4]; TD d[7]; int packBlocks; };

__global__ __launch_bounds__(256) void prep_all_k(PAll a) {
  if ((int)blockIdx.x < a.packBlocks) {
    int idx = blockIdx.x * 256 + threadIdx.x;
    PackD d = a.p[0]; int base = 0;
#pragma unroll
    for (int i = 1; i < 4; ++i) if (idx >= a.p[i - 1].n4) { d = a.p[i]; base = a.p[i - 1].n4; }
    if (idx >= d.n4) return;
    int e = (idx - base) * 4;
    int m = e / d.W;
    int c = e - m * d.W;
    const float4 v = *reinterpret_cast<const float4*>(d.src + e);
    bf16x4 o;
    o[0] = (bf16)v.x; o[1] = (bf16)v.y; o[2] = (bf16)v.z; o[3] = (bf16)v.w;
    *reinterpret_cast<bf16x4*>(d.dst + (size_t)m * d.ld + d.off + c) = o;
    return;
  }
  // transpose path
  int bid = blockIdx.x - a.packBlocks;
  TD d = a.d[0];
#pragma unroll
  for (int i = 1; i < 7; ++i) if (bid >= a.d[i].start) d = a.d[i];
  int local = bid - d.start;
  int k0 = (local % d.ntx) * 32;
  int n0 = (local / d.ntx) * 32;
  __shared__ float t[32][33];
  const int tx = threadIdx.x & 31, ty = threadIdx.x >> 5;
#pragma unroll
  for (int i = 0; i < 4; ++i) {
    int k = k0 + ty + i * 8;
    float v = d.src[(size_t)k * d.Ncols + n0 + tx];
    if (d.mode == 1 && k == (n0 + tx)) v = 0.f;
    if (d.mode == 2) v *= d.msk[(size_t)k * d.Ncols + n0 + tx];
    t[ty + i * 8][tx] = v;
  }
  __syncthreads();
#pragma unroll
  for (int i = 0; i < 4; ++i) {
    int n = n0 + ty + i * 8;
    d.dst[(size_t)n * d.ld_dst + d.k_off + k0 + tx] = (bf16)t[tx][ty + i * 8];
  }
}

// ---------------------------------------------------------------------------
// GEMM: 8-wave (512 thr) 2-phase double-buffered m97-style body.
// C[M][N] = A[M][K] (bf16 row-major) * B^T[N][K]; BK=32; waves 2(M)x4(N).
// epi 0: pre = acc + bias[col] (+ radd); h = hin*0.9 + relu(pre)*0.1
//        -> fp32 outf + bf16 nxt     epi 1: fp32 store of acc
// ---------------------------------------------------------------------------
struct GP {
  const bf16* A; const bf16* B;
  int K, lda, ldb;
  const float* hin; const float* bias; const float* radd;
  float* outf; int ld_out;
  bf16* nxt; int ld_nxt;
  int epi;
};

__device__ __forceinline__ void gload16(const bf16* g, bf16* l) {
  __builtin_amdgcn_global_load_lds(
      (const __attribute__((address_space(1))) void*)g,
      (__attribute__((address_space(3))) void*)l, 16, 0, 0);
}

template<int BM, int BN>
__device__ __forceinline__ void gemm_body8(const GP p) {
  constexpr int BK = 32;
  constexpr int WM = BM / 2, WN = BN / 4;      // 2x4 wave grid
  constexpr int FM = WM / 16, FN = WN / 16;
  __shared__ bf16 As[2][BM][BK];
  __shared__ bf16 Bs[2][BN][BK];
  const int tid  = threadIdx.x;
  const int lane = tid & 63;
  const int wave = tid >> 6;                   // 0..7
  // XCD-aware swizzle (all grids are multiples of 8 blocks per z-slice)
  const int gx = gridDim.x, nwg = gx * gridDim.y;
  const int lid = blockIdx.x + gx * blockIdx.y;
  const int q = nwg >> 3;
  const int swz = (lid & 7) * q + (lid >> 3);
  const int m0 = (swz / gx) * BM, n0 = (swz % gx) * BN;
  const int wm0 = (wave >> 2) * WM, wn0 = (wave & 3) * WN;
  const int lrow = lane >> 2;                  // row within 16-row chunk
  const int lcolE = (lane & 3) * 8;            // element col within BK
  const int frow = lane & 15;
  const int fk   = (lane >> 4) * 8;

  f32x4 acc[FM][FN];
#pragma unroll
  for (int i = 0; i < FM; ++i)
#pragma unroll
    for (int j = 0; j < FN; ++j)
#pragma unroll
      for (int r = 0; r < 4; ++r) acc[i][j][r] = 0.f;

  auto stage = [&](int buf, int t) {
    const int k0 = t * BK;
#pragma unroll
    for (int c = wave; c < BM / 16; c += 8) {
      const bf16* g = p.A + (size_t)(m0 + c * 16 + lrow) * p.lda + k0 + lcolE;
      gload16(g, &As[buf][0][0] + c * 512);
    }
#pragma unroll
    for (int c = wave; c < BN / 16; c += 8) {
      const bf16* g = p.B + (size_t)(n0 + c * 16 + lrow) * p.ldb + k0 + lcolE;
      gload16(g, &Bs[buf][0][0] + c * 512);
    }
  };

  const int nt = p.K / BK;
  stage(0, 0);
  __syncthreads();
  int cur = 0;
  for (int t = 0; t < nt; ++t) {
    if (t + 1 < nt) stage(cur ^ 1, t + 1);     // next tile's loads in flight
    bf16x8 af[FM], bfrag[FN];
#pragma unroll
    for (int i = 0; i < FM; ++i)
      af[i] = *reinterpret_cast<const bf16x8*>(&As[cur][wm0 + i * 16 + frow][fk]);
#pragma unroll
    for (int j = 0; j < FN; ++j)
      bfrag[j] = *reinterpret_cast<const bf16x8*>(&Bs[cur][wn0 + j * 16 + frow][fk]);
#pragma unroll
    for (int i = 0; i < FM; ++i)
#pragma unroll
      for (int j = 0; j < FN; ++j)
        acc[i][j] = __builtin_amdgcn_mfma_f32_16x16x32_bf16(af[i], bfrag[j], acc[i][j], 0, 0, 0);
    __syncthreads();                           // drains stage's vmcnt + reuse fence
    cur ^= 1;
  }

  // epilogue: C/D layout col = lane&15, row = (lane>>4)*4 + reg
#pragma unroll
  for (int i = 0; i < FM; ++i) {
#pragma unroll
    for (int j = 0; j < FN; ++j) {
#pragma unroll
      for (int r = 0; r < 4; ++r) {
        int row = m0 + wm0 + i * 16 + (lane >> 4) * 4 + r;
        int col = n0 + wn0 + j * 16 + (lane & 15);
        float v = acc[i][j][r];
        size_t oidx = (size_t)row * p.ld_out + col;
        if (p.epi == 0) {
          float pre = v + p.bias[col];
          if (p.radd) pre += p.radd[oidx];
          float h = p.hin[oidx] * 0.9f + fmaxf(pre, 0.f) * 0.1f;
          p.outf[oidx] = h;
          p.nxt[(size_t)row * p.ld_nxt + col] = (bf16)h;
        } else {
          p.outf[oidx] = v;
        }
      }
    }
  }
}

template<int BM, int BN>
__global__ __launch_bounds__(512) void gemm_one(GP p) { gemm_body8<BM, BN>(p); }

__global__ __launch_bounds__(512) void gemm_tri(GP p0, GP p1, GP p2) {
  GP p;
  if (blockIdx.z == 0) p = p0;
  else if (blockIdx.z == 1) p = p1;
  else p = p2;
  gemm_body8<128, 128>(p);
}

// ---------------------------------------------------------------------------
extern "C" void kernel_launch(void* const* d_in, const int* in_sizes, int n_in,
                              void* d_out, int out_size, void* d_ws, size_t ws_size,
                              hipStream_t stream) {
  const float* x        = (const float*)d_in[0];
  const float* h0_in    = (const float*)d_in[1];
  const float* h1_in    = (const float*)d_in[2];
  const float* h2_in    = (const float*)d_in[3];
  const float* i_to_h0  = (const float*)d_in[4];
  const float* h0_w     = (const float*)d_in[5];
  const float* h0_b     = (const float*)d_in[6];
  const float* h0_to_h1 = (const float*)d_in[7];
  const float* h1_w     = (const float*)d_in[8];
  const float* h1_b     = (const float*)d_in[9];
  const float* h1_to_h2 = (const float*)d_in[10];
  const float* h2_w     = (const float*)d_in[11];
  const float* h2_b     = (const float*)d_in[12];
  const float* w_out    = (const float*)d_in[13];
  const float* m01      = (const float*)d_in[14];
  const float* m12      = (const float*)d_in[15];
  float* out = (float*)d_out;

  uint8_t* ws = (uint8_t*)d_ws;
  constexpr size_t OFF_A0  = 0;                    // [2048][2560] A of S0
  constexpr size_t OFF_W0  = OFF_A0 + 10485760;    // [2048][2560] B^T of S0
  constexpr size_t OFF_W1R = OFF_W0 + 10485760;    // [2048][2048] h1_w'^T
  constexpr size_t OFF_W2R = OFF_W1R + 8388608;    // [2048][2048] h2_w'^T
  constexpr size_t OFF_W01 = OFF_W2R + 8388608;    // [2048][2048] h01m^T
  constexpr size_t OFF_W12 = OFF_W01 + 8388608;    // [2048][2048] h12m^T
  constexpr size_t OFF_WO  = OFF_W12 + 8388608;    // [128][2048]  w_out^T
  constexpr size_t OFF_AR1 = OFF_WO + 524288;      // h1_in bf16 -> later h1 bf16
  constexpr size_t OFF_AR2 = OFF_AR1 + 8388608;    // h2_in bf16 -> later h2 bf16
  constexpr size_t OFF_AH0 = OFF_AR2 + 8388608;    // h0 bf16
  constexpr size_t WS_NEED = OFF_AH0 + 8388608;    // ~80.2 MB
  if (ws_size < WS_NEED) return;

  bf16* A0  = (bf16*)(ws + OFF_A0);
  bf16* Wt0 = (bf16*)(ws + OFF_W0);
  bf16* W1r = (bf16*)(ws + OFF_W1R);
  bf16* W2r = (bf16*)(ws + OFF_W2R);
  bf16* W01 = (bf16*)(ws + OFF_W01);
  bf16* W12 = (bf16*)(ws + OFF_W12);
  bf16* WtO = (bf16*)(ws + OFF_WO);
  bf16* Ar1 = (bf16*)(ws + OFF_AR1);
  bf16* Ar2 = (bf16*)(ws + OFF_AR2);
  bf16* Ah0 = (bf16*)(ws + OFF_AH0);
  bf16* Ah1 = Ar1;   // h1_in bf16 dead after D1
  bf16* Ah2 = Ar2;   // h2_in bf16 dead after D1

  float* o_h0  = out;
  float* o_h1  = out + (size_t)BB * NN;
  float* o_h2  = out + (size_t)2 * BB * NN;
  float* o_out = out + (size_t)3 * BB * NN;

  // --- fused prep (1 dispatch) ---
  PAll pa;
  int n4a = BB * ISZ / 4;                 // x -> A0[:, 0:512]
  int n4b = n4a + BB * NN / 4;            // h0_in -> A0[:, 512:2560]
  int n4c = n4b + BB * NN / 4;            // h1_in -> Ar1
  int n4d = n4c + BB * NN / 4;            // h2_in -> Ar2
  pa.p[0] = {x,     A0,  ISZ, ISZ + NN, 0,   n4a};
  pa.p[1] = {h0_in, A0,  NN,  ISZ + NN, ISZ, n4b};
  pa.p[2] = {h1_in, Ar1, NN,  NN,       0,   n4c};
  pa.p[3] = {h2_in, Ar2, NN,  NN,       0,   n4d};
  pa.packBlocks = (n4d + 255) / 256;
  int s0 = 0;
  pa.d[0] = {i_to_h0,  nullptr, Wt0, NN,  ISZ + NN, 0,   0, ISZ / 32, s0}; s0 += (ISZ / 32) * (NN / 32);
  pa.d[1] = {h0_w,     nullptr, Wt0, NN,  ISZ + NN, ISZ, 1, NN / 32,  s0}; s0 += (NN / 32) * (NN / 32);
  pa.d[2] = {h1_w,     nullptr, W1r, NN,  NN,       0,   1, NN / 32,  s0}; s0 += (NN / 32) * (NN / 32);
  pa.d[3] = {h2_w,     nullptr, W2r, NN,  NN,       0,   1, NN / 32,  s0}; s0 += (NN / 32) * (NN / 32);
  pa.d[4] = {h0_to_h1, m01,     W01, NN,  NN,       0,   2, NN / 32,  s0}; s0 += (NN / 32) * (NN / 32);
  pa.d[5] = {h1_to_h2, m12,     W12, NN,  NN,       0,   2, NN / 32,  s0}; s0 += (NN / 32) * (NN / 32);
  pa.d[6] = {w_out,    nullptr, WtO, OSZ, NN,       0,   0, NN / 32,  s0}; s0 += (NN / 32) * (OSZ / 32);
  prep_all_k<<<pa.packBlocks + s0, 256, 0, stream>>>(pa);

  // --- D1: S0 (h0) + R1 + R2 in one 768-block dispatch ---
  GP pS0{A0,  Wt0, ISZ + NN, ISZ + NN, ISZ + NN, h0_in, h0_b, nullptr,
         o_h0, NN, Ah0, NN, 0};
  GP pR1{Ar1, W1r, NN, NN, NN, nullptr, nullptr, nullptr, o_h1, NN, nullptr, 0, 1};
  GP pR2{Ar2, W2r, NN, NN, NN, nullptr, nullptr, nullptr, o_h2, NN, nullptr, 0, 1};
  gemm_tri<<<dim3(NN / 128, BB / 128, 3), 512, 0, stream>>>(pS0, pR1, pR2);

  // --- D2: F1 = h0@W01 (+R1) -> h1 ---
  GP pF1{Ah0, W01, NN, NN, NN, h1_in, h1_b, o_h1, o_h1, NN, Ah1, NN, 0};
  gemm_one<128, 128><<<dim3(NN / 128, BB / 128), 512, 0, stream>>>(pF1);

  // --- D3: F2 = h1@W12 (+R2) -> h2 ---
  GP pF2{Ah1, W12, NN, NN, NN, h2_in, h2_b, o_h2, o_h2, NN, Ah2, NN, 0};
  gemm_one<128, 128><<<dim3(NN / 128, BB / 128), 512, 0, stream>>>(pF2);

  // --- D4: out = h2 @ w_out ---
  GP pO{Ah2, WtO, NN, NN, NN, nullptr, nullptr, nullptr, o_out, OSZ, nullptr, 0, 1};
  gemm_one<32, 64><<<dim3(OSZ / 64, BB / 32), 512, 0, stream>>>(pO);
}